// Round 9
// baseline (145.317 us; speedup 1.0000x reference)
//
#include <hip/hip_runtime.h>
#include <hip/hip_bf16.h>

typedef __attribute__((ext_vector_type(8))) short short8;
typedef __attribute__((ext_vector_type(2))) float f32x2;
typedef __attribute__((ext_vector_type(4))) float f32x4;

__device__ __forceinline__ unsigned short f2bf(float x) {
    unsigned int u = __float_as_uint(x);
    unsigned int lsb = (u >> 16) & 1u;
    u += 0x7fffu + lsb;                    // round-to-nearest-even
    return (unsigned short)(u >> 16);
}

__device__ __forceinline__ float bf_lo(unsigned g) {   // low ushort -> f32
    return __uint_as_float(g << 16);
}
__device__ __forceinline__ float bf_hi(unsigned g) {   // high ushort -> f32
    return __uint_as_float(g & 0xffff0000u);
}

__device__ __forceinline__ short8 pack8(f32x4 a, f32x4 b) {
    short8 r;
    r[0] = (short)f2bf(a.x); r[1] = (short)f2bf(a.y);
    r[2] = (short)f2bf(a.z); r[3] = (short)f2bf(a.w);
    r[4] = (short)f2bf(b.x); r[5] = (short)f2bf(b.y);
    r[6] = (short)f2bf(b.z); r[7] = (short)f2bf(b.w);
    return r;
}

// Standalone init (fallback path): out[n][c] = bias[c]
__global__ __launch_bounds__(256) void k_init(const float* __restrict__ bias,
                                              float* __restrict__ out, long total4) {
    long i4 = (long)blockIdx.x * 256 + threadIdx.x;
    if (i4 < total4) {
        const f32x4* b4 = (const f32x4*)bias;
        ((f32x4*)out)[i4] = b4[i4 & 15];
    }
}

// Fused: blocks [0,gblocks) compute G = (feat @ W.T) in bf16 via MFMA;
// blocks [gblocks, ...) broadcast bias into out.
// NOTE: out init must be a PLAIN store — NT store streamed it to HBM and made
// every later atomic flush RMW against HBM (R4: WRITE_SIZE doubled, +22 us).
__global__ __launch_bounds__(256) void k_setup(const float* __restrict__ feat,
                                               const float* __restrict__ W,
                                               const float* __restrict__ bias,
                                               unsigned short* __restrict__ G,
                                               float* __restrict__ out,
                                               int N, int gblocks) {
    if ((int)blockIdx.x >= gblocks) {
        long i4 = (long)(blockIdx.x - gblocks) * 256 + threadIdx.x;
        long total4 = (long)N * 16;            // N*64 floats / 4
        if (i4 < total4) {
            const f32x4* b4 = (const f32x4*)bias;
            ((f32x4*)out)[i4] = b4[i4 & 15];   // plain store: stay dirty in L2
        }
        return;
    }

    int wave = blockIdx.x * 4 + (threadIdx.x >> 6);
    int lane = threadIdx.x & 63;
    int m0 = wave * 16;
    if (m0 >= N) return;
    int n = lane & 15;
    int quad = lane >> 4;

    // B fragments: B[k][c0+n] = W[c0+n][k]; k = ks*32 + quad*8 + j
    short8 bf[4][2];
#pragma unroll
    for (int ct = 0; ct < 4; ++ct)
#pragma unroll
        for (int ks = 0; ks < 2; ++ks) {
            const f32x4* wp = (const f32x4*)(W + (size_t)(ct * 16 + n) * 64 + ks * 32 + quad * 8);
            f32x4 w0 = wp[0];
            f32x4 w1 = wp[1];
            bf[ct][ks] = pack8(w0, w1);
        }

    // A fragments: A[m0+n][k]  (NT load: feat read exactly once)
    int mrow = m0 + n; if (mrow >= N) mrow = N - 1;
    short8 af[2];
#pragma unroll
    for (int ks = 0; ks < 2; ++ks) {
        const f32x4* ap = (const f32x4*)(feat + (size_t)mrow * 64 + ks * 32 + quad * 8);
        f32x4 a0 = __builtin_nontemporal_load(ap);
        f32x4 a1 = __builtin_nontemporal_load(ap + 1);
        af[ks] = pack8(a0, a1);
    }

    f32x4 acc[4];
#pragma unroll
    for (int ct = 0; ct < 4; ++ct) {
        acc[ct] = (f32x4){0.f, 0.f, 0.f, 0.f};
#pragma unroll
        for (int ks = 0; ks < 2; ++ks)
            acc[ct] = __builtin_amdgcn_mfma_f32_16x16x32_bf16(af[ks], bf[ct][ks], acc[ct], 0, 0, 0);
    }

    // D layout: col = lane&15 (=n), row = quad*4 + reg. Plain stores: G is
    // re-read by k_spmm, keep it in L2/L3.
#pragma unroll
    for (int ct = 0; ct < 4; ++ct)
#pragma unroll
        for (int r = 0; r < 4; ++r) {
            int rowm = m0 + quad * 4 + r;
            if (rowm < N)
                G[(size_t)rowm * 64 + ct * 16 + n] = f2bf(acc[ct][r]);
        }
}

// SpMM: out[row] += val * G[col]. Sorted rows. 128 edges/wave (64 pairs).
// R9: 2 edges per gather instr — half-wave h=0 serves the even edge of a
// pair, h=1 the odd edge; each lane loads one dword (channels 2s,2s+1) of
// its edge's G row. 16 loads in flight cover 32 edges -> per-wave serial
// wait-phases halve (8 -> 4) vs the 1-edge/instr structure.
// Flush: acc halves combined via shfl_xor(32); first/last rows of the wave
// may be shared across waves -> atomicAdd; interior rows exclusively owned
// -> plain coalesced float2 store out[row] = bias + acc.
__global__ __launch_bounds__(256) void k_spmm(const unsigned* __restrict__ Gd,
                                              const int* __restrict__ erow,
                                              const int* __restrict__ ecol,
                                              const float* __restrict__ evalv,
                                              const float* __restrict__ bias,
                                              float* __restrict__ out, int E) {
    int wave = blockIdx.x * 4 + (threadIdx.x >> 6);
    int lane = threadIdx.x & 63;
    int h = lane >> 5;          // 0: even edge of pair, 1: odd
    int s = lane & 31;          // channel-pair index: channels 2s, 2s+1
    long base0 = (long)wave * 128;
    if (base0 >= E) return;

    float b0 = bias[2 * s];
    float b1 = bias[2 * s + 1];
    float acc0 = 0.f, acc1 = 0.f;
    int cur;
    bool first = true;          // first flushed row may be shared w/ prev wave

#define FLUSH(ROW)                                                             \
    {                                                                          \
        float a0 = acc0 + __shfl_xor(acc0, 32, 64);                            \
        float a1 = acc1 + __shfl_xor(acc1, 32, 64);                            \
        float* p = out + ((size_t)(unsigned)(ROW) << 6) + (s << 1);            \
        if (first) {                                                           \
            if (h == 0) { atomicAdd(p, a0); atomicAdd(p + 1, a1); }            \
            first = false;                                                     \
        } else if (h == 0) {                                                   \
            f32x2 st = {b0 + a0, b1 + a1};                                     \
            *(f32x2*)p = st;                                                   \
        }                                                                      \
    }

    if (base0 + 128 <= E) {
        // ---- fast path: full 128-edge segment ----
        for (int ch = 0; ch < 2; ++ch) {
            long base = base0 + (long)ch * 64 + lane;
            int rv = __builtin_nontemporal_load(erow + base);
            int cv = __builtin_nontemporal_load(ecol + base);
            int vv = __float_as_int(__builtin_nontemporal_load(evalv + base));
            if (ch == 0) cur = __builtin_amdgcn_readlane(rv, 0);

#pragma unroll
            for (int j0 = 0; j0 < 32; j0 += 16) {
                unsigned g[16];
                // issue 16 paired gathers (32 edges), then consume
#pragma unroll
                for (int u = 0; u < 16; ++u) {
                    int p = j0 + u;
                    int c0 = __builtin_amdgcn_readlane(cv, 2 * p);
                    int c1 = __builtin_amdgcn_readlane(cv, 2 * p + 1);
                    int cc = h ? c1 : c0;
                    g[u] = Gd[(size_t)(unsigned)cc * 32u + (unsigned)s];
                }
#pragma unroll
                for (int u = 0; u < 16; ++u) {
                    int p = j0 + u;
                    int r0 = __builtin_amdgcn_readlane(rv, 2 * p);      // SGPR
                    int r1 = __builtin_amdgcn_readlane(rv, 2 * p + 1);  // SGPR
                    float v0 = __int_as_float(__builtin_amdgcn_readlane(vv, 2 * p));
                    float v1 = __int_as_float(__builtin_amdgcn_readlane(vv, 2 * p + 1));
                    float g0 = bf_lo(g[u]);
                    float g1 = bf_hi(g[u]);
                    if (r0 == cur && r1 == cur) {          // scalar fast path
                        float vh = h ? v1 : v0;
                        acc0 = fmaf(vh, g0, acc0);
                        acc1 = fmaf(vh, g1, acc1);
                    } else {                               // row boundary in pair
                        if (r0 != cur) {
                            FLUSH(cur);
                            acc0 = 0.f; acc1 = 0.f; cur = r0;
                        }
                        float ve0 = h ? 0.f : v0;          // even edge only
                        acc0 = fmaf(ve0, g0, acc0);
                        acc1 = fmaf(ve0, g1, acc1);
                        if (r1 != cur) {
                            FLUSH(cur);
                            acc0 = 0.f; acc1 = 0.f; cur = r1;
                        }
                        float ve1 = h ? v1 : 0.f;          // odd edge only
                        acc0 = fmaf(ve1, g0, acc0);
                        acc1 = fmaf(ve1, g1, acc1);
                    }
                }
            }
        }
    } else {
        // ---- tail path: per-edge, both halves duplicate the edge with h==1
        // contributing zero so FLUSH's combine stays correct ----
        cur = __builtin_amdgcn_readfirstlane(erow[base0]);
        for (long e = base0; e < E; ++e) {
            int r = erow[e];
            int c = ecol[e];
            float v = evalv[e];
            unsigned g = Gd[(size_t)(unsigned)c * 32u + (unsigned)s];
            if (r != cur) {
                FLUSH(cur);
                acc0 = 0.f; acc1 = 0.f; cur = r;
            }
            float ve = h ? 0.f : v;
            acc0 = fmaf(ve, bf_lo(g), acc0);
            acc1 = fmaf(ve, bf_hi(g), acc1);
        }
    }

    // last row may be shared with the next wave -> always atomic
    {
        float a0 = acc0 + __shfl_xor(acc0, 32, 64);
        float a1 = acc1 + __shfl_xor(acc1, 32, 64);
        if (h == 0) {
            float* p = out + ((size_t)(unsigned)cur << 6) + (s << 1);
            atomicAdd(p, a0);
            atomicAdd(p + 1, a1);
        }
    }
#undef FLUSH
}

// Fallback if ws too small: fused f32 gather + shfl transform at flush.
__global__ __launch_bounds__(256) void k_fused(const float* __restrict__ feat,
                                               const int* __restrict__ erow,
                                               const int* __restrict__ ecol,
                                               const float* __restrict__ evalv,
                                               const float* __restrict__ W,
                                               float* __restrict__ out,
                                               int E, int epw) {
    __shared__ float Wt[64 * 64];
    for (int i = threadIdx.x; i < 4096; i += 256) {
        int c = i >> 6, f = i & 63;
        Wt[f * 64 + c] = W[i];
    }
    __syncthreads();

    int wave = blockIdx.x * 4 + (threadIdx.x >> 6);
    int lane = threadIdx.x & 63;
    long e0 = (long)wave * epw;
    if (e0 >= E) return;
    long e1 = e0 + epw; if (e1 > E) e1 = E;

    int cur = erow[e0];
    float acc = 0.f;
    for (long e = e0; e < e1; ++e) {
        int r = erow[e];
        int c = ecol[e];
        float v = evalv[e];
        float g = feat[((size_t)c << 6) | lane];
        if (r != cur) {
            float res = 0.f;
#pragma unroll
            for (int f = 0; f < 64; ++f)
                res += __shfl(acc, f, 64) * Wt[f * 64 + lane];
            atomicAdd(out + ((size_t)cur << 6) + lane, res);
            acc = 0.f;
            cur = r;
        }
        acc += v * g;
    }
    {
        float res = 0.f;
#pragma unroll
        for (int f = 0; f < 64; ++f)
            res += __shfl(acc, f, 64) * Wt[f * 64 + lane];
        atomicAdd(out + ((size_t)cur << 6) + lane, res);
    }
}

extern "C" void kernel_launch(void* const* d_in, const int* in_sizes, int n_in,
                              void* d_out, int out_size, void* d_ws, size_t ws_size,
                              hipStream_t stream) {
    const float* feat  = (const float*)d_in[0];
    const int*   erow  = (const int*)d_in[1];
    const int*   ecol  = (const int*)d_in[2];
    const float* evalv = (const float*)d_in[3];
    const float* W     = (const float*)d_in[4];
    const float* bias  = (const float*)d_in[5];
    float* out = (float*)d_out;

    int N = in_sizes[0] / 64;
    int E = in_sizes[1];

    size_t need = (size_t)N * 64 * sizeof(unsigned short);
    if (ws_size >= need) {
        unsigned short* G = (unsigned short*)d_ws;
        int tiles = (N + 15) / 16;
        int gblocks = (tiles + 3) / 4;
        long total4 = (long)N * 16;
        int iblocks = (int)((total4 + 255) / 256);
        k_setup<<<gblocks + iblocks, 256, 0, stream>>>(feat, W, bias, G, out, N, gblocks);

        int nwaves = (E + 127) / 128;            // 128 edges/wave
        int nblocks = (nwaves + 3) / 4;
        k_spmm<<<nblocks, 256, 0, stream>>>((const unsigned*)G, erow, ecol, evalv, bias, out, E);
    } else {
        long total4 = (long)N * 16;
        k_init<<<(int)((total4 + 255) / 256), 256, 0, stream>>>(bias, out, total4);
        int epw = (E + 8191) / 8192;
        if (epw < 32) epw = 32;
        int nwaves = (E + epw - 1) / epw;
        int nblocks = (nwaves + 3) / 4;
        k_fused<<<nblocks, 256, 0, stream>>>(feat, erow, ecol, evalv, W, out, E, epw);
    }
}

// Round 10
// 140.069 us; speedup vs baseline: 1.0375x; 1.0375x over previous
//
#include <hip/hip_runtime.h>
#include <hip/hip_bf16.h>

// FINAL (R10 = R8, best timed 139.7 us).
// Conclusion of the session's elimination matrix (R5-R9): k_spmm is bound by
// Infinity-Cache random-line service (~1.6M random 128B G-rows, 12.8MB
// working set > per-XCD L2), not by VALU, SMEM, VMEM issue, atomics, or
// outstanding-load depth — each was cut 2-4x individually with no timed
// movement. ~90us of the ~140us total is harness-fixed (poison fills +
// input restores).

typedef __attribute__((ext_vector_type(8))) short short8;
typedef __attribute__((ext_vector_type(4))) float f32x4;

__device__ __forceinline__ unsigned short f2bf(float x) {
    unsigned int u = __float_as_uint(x);
    unsigned int lsb = (u >> 16) & 1u;
    u += 0x7fffu + lsb;                    // round-to-nearest-even
    return (unsigned short)(u >> 16);
}

__device__ __forceinline__ float bf2f(unsigned int b16) {
    return __uint_as_float(b16 << 16);
}

__device__ __forceinline__ short8 pack8(f32x4 a, f32x4 b) {
    short8 r;
    r[0] = (short)f2bf(a.x); r[1] = (short)f2bf(a.y);
    r[2] = (short)f2bf(a.z); r[3] = (short)f2bf(a.w);
    r[4] = (short)f2bf(b.x); r[5] = (short)f2bf(b.y);
    r[6] = (short)f2bf(b.z); r[7] = (short)f2bf(b.w);
    return r;
}

// Standalone init (fallback path): out[n][c] = bias[c]
__global__ __launch_bounds__(256) void k_init(const float* __restrict__ bias,
                                              float* __restrict__ out, long total4) {
    long i4 = (long)blockIdx.x * 256 + threadIdx.x;
    if (i4 < total4) {
        const f32x4* b4 = (const f32x4*)bias;
        ((f32x4*)out)[i4] = b4[i4 & 15];
    }
}

// Fused: blocks [0,gblocks) compute G = (feat @ W.T) in bf16 via MFMA;
// blocks [gblocks, ...) broadcast bias into out.
// NOTE: out init must be a PLAIN store — NT store streamed it to HBM and made
// every later atomic flush RMW against HBM (R4: WRITE_SIZE doubled, +22 us).
__global__ __launch_bounds__(256) void k_setup(const float* __restrict__ feat,
                                               const float* __restrict__ W,
                                               const float* __restrict__ bias,
                                               unsigned short* __restrict__ G,
                                               float* __restrict__ out,
                                               int N, int gblocks) {
    if ((int)blockIdx.x >= gblocks) {
        long i4 = (long)(blockIdx.x - gblocks) * 256 + threadIdx.x;
        long total4 = (long)N * 16;            // N*64 floats / 4
        if (i4 < total4) {
            const f32x4* b4 = (const f32x4*)bias;
            ((f32x4*)out)[i4] = b4[i4 & 15];   // plain store: stay dirty in L2
        }
        return;
    }

    int wave = blockIdx.x * 4 + (threadIdx.x >> 6);
    int lane = threadIdx.x & 63;
    int m0 = wave * 16;
    if (m0 >= N) return;
    int n = lane & 15;
    int quad = lane >> 4;

    // B fragments: B[k][c0+n] = W[c0+n][k]; k = ks*32 + quad*8 + j
    short8 bf[4][2];
#pragma unroll
    for (int ct = 0; ct < 4; ++ct)
#pragma unroll
        for (int ks = 0; ks < 2; ++ks) {
            const f32x4* wp = (const f32x4*)(W + (size_t)(ct * 16 + n) * 64 + ks * 32 + quad * 8);
            f32x4 w0 = wp[0];
            f32x4 w1 = wp[1];
            bf[ct][ks] = pack8(w0, w1);
        }

    // A fragments: A[m0+n][k]  (NT load: feat read exactly once)
    int mrow = m0 + n; if (mrow >= N) mrow = N - 1;
    short8 af[2];
#pragma unroll
    for (int ks = 0; ks < 2; ++ks) {
        const f32x4* ap = (const f32x4*)(feat + (size_t)mrow * 64 + ks * 32 + quad * 8);
        f32x4 a0 = __builtin_nontemporal_load(ap);
        f32x4 a1 = __builtin_nontemporal_load(ap + 1);
        af[ks] = pack8(a0, a1);
    }

    f32x4 acc[4];
#pragma unroll
    for (int ct = 0; ct < 4; ++ct) {
        acc[ct] = (f32x4){0.f, 0.f, 0.f, 0.f};
#pragma unroll
        for (int ks = 0; ks < 2; ++ks)
            acc[ct] = __builtin_amdgcn_mfma_f32_16x16x32_bf16(af[ks], bf[ct][ks], acc[ct], 0, 0, 0);
    }

    // D layout: col = lane&15 (=n), row = quad*4 + reg. Plain stores: G is
    // re-read by k_spmm, keep it in L2/L3.
#pragma unroll
    for (int ct = 0; ct < 4; ++ct)
#pragma unroll
        for (int r = 0; r < 4; ++r) {
            int rowm = m0 + quad * 4 + r;
            if (rowm < N)
                G[(size_t)rowm * 64 + ct * 16 + n] = f2bf(acc[ct][r]);
        }
}

// SpMM: out[row] += val * G[col]. Sorted rows. 128 edges/wave.
// Metadata loaded up front (6 NT vector loads); readlane-broadcast ->
// bookkeeping in SGPRs (scalar flush branch); gathers issued 16-ahead.
// Flush: first/last rows may be shared across waves -> atomicAdd; interior
// rows are exclusively owned -> plain coalesced store out[row] = bias + acc.
__global__ __launch_bounds__(256) void k_spmm(const unsigned short* __restrict__ G,
                                              const int* __restrict__ erow,
                                              const int* __restrict__ ecol,
                                              const float* __restrict__ evalv,
                                              const float* __restrict__ bias,
                                              float* __restrict__ out, int E) {
    int wave = blockIdx.x * 4 + (threadIdx.x >> 6);
    int lane = threadIdx.x & 63;
    long base0 = (long)wave * 128;
    if (base0 >= E) return;

    float blane = bias[lane];
    int cur;
    float acc = 0.f;
    bool first = true;             // first flushed row may be shared w/ prev wave

    if (base0 + 128 <= E) {
        // ---- fast path: full 128-edge segment, fully unrolled pipeline ----
        long i0 = base0 + lane;
        int rv[2], cv[2], vv[2];
        rv[0] = __builtin_nontemporal_load(erow + i0);
        cv[0] = __builtin_nontemporal_load(ecol + i0);
        vv[0] = __float_as_int(__builtin_nontemporal_load(evalv + i0));
        rv[1] = __builtin_nontemporal_load(erow + i0 + 64);
        cv[1] = __builtin_nontemporal_load(ecol + i0 + 64);
        vv[1] = __float_as_int(__builtin_nontemporal_load(evalv + i0 + 64));

        cur = __builtin_amdgcn_readlane(rv[0], 0);

        unsigned g[2][16];          // raw ushort gather results (double buffer)
        // prologue: issue group 0
#pragma unroll
        for (int u = 0; u < 16; ++u) {
            int c = __builtin_amdgcn_readlane(cv[0], u);
            g[0][u] = G[((size_t)(unsigned)c << 6) | (unsigned)lane];
        }
#pragma unroll
        for (int j = 0; j < 8; ++j) {
            // issue group j+1 into the other buffer before consuming group j
            if (j < 7) {
                int chp = (j + 1) >> 2, jop = ((j + 1) & 3) * 16;
#pragma unroll
                for (int u = 0; u < 16; ++u) {
                    int c = __builtin_amdgcn_readlane(cv[chp], jop + u);
                    g[(j + 1) & 1][u] = G[((size_t)(unsigned)c << 6) | (unsigned)lane];
                }
            }
            int ch = j >> 2, jo = (j & 3) * 16;
#pragma unroll
            for (int u = 0; u < 16; ++u) {
                int r = __builtin_amdgcn_readlane(rv[ch], jo + u);   // SGPR
                float v = __int_as_float(__builtin_amdgcn_readlane(vv[ch], jo + u));
                if (r != cur) {                                       // scalar branch
                    if (first) {
                        atomicAdd(out + ((size_t)(unsigned)cur << 6) + lane, acc);
                        first = false;
                    } else {
                        out[((size_t)(unsigned)cur << 6) + lane] = blane + acc;
                    }
                    acc = 0.f;
                    cur = r;
                }
                acc = fmaf(v, bf2f(g[j & 1][u]), acc);
            }
        }
    } else {
        // ---- tail path: generic per-edge loop ----
        cur = __builtin_amdgcn_readfirstlane(erow[base0]);
        long e1 = E;
        for (long e = base0; e < e1; ++e) {
            int r = erow[e];
            int c = ecol[e];
            float v = evalv[e];
            float gg = bf2f(G[((size_t)(unsigned)c << 6) | (unsigned)lane]);
            if (r != cur) {
                if (first) {
                    atomicAdd(out + ((size_t)(unsigned)cur << 6) + lane, acc);
                    first = false;
                } else {
                    out[((size_t)(unsigned)cur << 6) + lane] = blane + acc;
                }
                acc = 0.f;
                cur = r;
            }
            acc = fmaf(v, gg, acc);
        }
    }

    // last row may be shared with the next wave -> always atomic
    atomicAdd(out + ((size_t)(unsigned)cur << 6) + lane, acc);
}

// Fallback if ws too small: fused f32 gather + shfl transform at flush.
__global__ __launch_bounds__(256) void k_fused(const float* __restrict__ feat,
                                               const int* __restrict__ erow,
                                               const int* __restrict__ ecol,
                                               const float* __restrict__ evalv,
                                               const float* __restrict__ W,
                                               float* __restrict__ out,
                                               int E, int epw) {
    __shared__ float Wt[64 * 64];
    for (int i = threadIdx.x; i < 4096; i += 256) {
        int c = i >> 6, f = i & 63;
        Wt[f * 64 + c] = W[i];
    }
    __syncthreads();

    int wave = blockIdx.x * 4 + (threadIdx.x >> 6);
    int lane = threadIdx.x & 63;
    long e0 = (long)wave * epw;
    if (e0 >= E) return;
    long e1 = e0 + epw; if (e1 > E) e1 = E;

    int cur = erow[e0];
    float acc = 0.f;
    for (long e = e0; e < e1; ++e) {
        int r = erow[e];
        int c = ecol[e];
        float v = evalv[e];
        float g = feat[((size_t)c << 6) | lane];
        if (r != cur) {
            float res = 0.f;
#pragma unroll
            for (int f = 0; f < 64; ++f)
                res += __shfl(acc, f, 64) * Wt[f * 64 + lane];
            atomicAdd(out + ((size_t)cur << 6) + lane, res);
            acc = 0.f;
            cur = r;
        }
        acc += v * g;
    }
    {
        float res = 0.f;
#pragma unroll
        for (int f = 0; f < 64; ++f)
            res += __shfl(acc, f, 64) * Wt[f * 64 + lane];
        atomicAdd(out + ((size_t)cur << 6) + lane, res);
    }
}

extern "C" void kernel_launch(void* const* d_in, const int* in_sizes, int n_in,
                              void* d_out, int out_size, void* d_ws, size_t ws_size,
                              hipStream_t stream) {
    const float* feat  = (const float*)d_in[0];
    const int*   erow  = (const int*)d_in[1];
    const int*   ecol  = (const int*)d_in[2];
    const float* evalv = (const float*)d_in[3];
    const float* W     = (const float*)d_in[4];
    const float* bias  = (const float*)d_in[5];
    float* out = (float*)d_out;

    int N = in_sizes[0] / 64;
    int E = in_sizes[1];

    size_t need = (size_t)N * 64 * sizeof(unsigned short);
    if (ws_size >= need) {
        unsigned short* G = (unsigned short*)d_ws;
        int tiles = (N + 15) / 16;
        int gblocks = (tiles + 3) / 4;
        long total4 = (long)N * 16;
        int iblocks = (int)((total4 + 255) / 256);
        k_setup<<<gblocks + iblocks, 256, 0, stream>>>(feat, W, bias, G, out, N, gblocks);

        int nwaves = (E + 127) / 128;            // 128 edges/wave
        int nblocks = (nwaves + 3) / 4;
        k_spmm<<<nblocks, 256, 0, stream>>>(G, erow, ecol, evalv, bias, out, E);
    } else {
        long total4 = (long)N * 16;
        k_init<<<(int)((total4 + 255) / 256), 256, 0, stream>>>(bias, out, total4);
        int epw = (E + 8191) / 8192;
        if (epw < 32) epw = 32;
        int nwaves = (E + epw - 1) / epw;
        int nblocks = (nwaves + 3) / 4;
        k_fused<<<nblocks, 256, 0, stream>>>(feat, erow, ecol, evalv, W, out, E, epw);
    }
}